// Round 5
// baseline (183.379 us; speedup 1.0000x reference)
//
#include <hip/hip_runtime.h>
#include <hip/hip_bf16.h>

#define T_DIM 2048

typedef __attribute__((ext_vector_type(8))) short short8_t;
typedef short8_t __attribute__((may_alias)) short8_a;
typedef __attribute__((ext_vector_type(4))) short short4_t;
typedef short4_t __attribute__((may_alias)) short4_a;
typedef __attribute__((ext_vector_type(4))) float f32x4;
typedef __attribute__((ext_vector_type(16))) float f32x16;
typedef __attribute__((ext_vector_type(4))) float float4_t;
typedef float4_t __attribute__((may_alias)) float4_a;
typedef __attribute__((ext_vector_type(4))) unsigned int u32x4;

__device__ __forceinline__ short f2bf(float f) {
    unsigned int u = __builtin_bit_cast(unsigned int, f);
    unsigned int r = (u + 0x7fffu + ((u >> 16) & 1u)) >> 16;
    return (short)r;
}

// async global->LDS, 16B per lane. lds dst must be wave-uniform base (+ lane*16 implicit).
__device__ __forceinline__ void gl_lds16(const short* g, short* l) {
    __builtin_amdgcn_global_load_lds(
        (const __attribute__((address_space(1))) void*)g,
        (__attribute__((address_space(3))) void*)l, 16, 0, 0);
}

// ---------------- fp32 -> bf16 cast: query + 4 weights in ONE launch ----------------
// dst regions are contiguous in ws: [query 4M][Wq 1M][Wk 1M][Wv 1M][Wo 1M]
__global__ __launch_bounds__(256) void cvt_all(const float* __restrict__ query,
                                               const float* __restrict__ Wq,
                                               const float* __restrict__ Wk,
                                               const float* __restrict__ Wv,
                                               const float* __restrict__ Wo,
                                               short* __restrict__ out) {
    const int bx = blockIdx.x;
    const int i = bx * 2048 + threadIdx.x * 8;
    const float* s;
    if (bx < 2048) {
        s = query + i;
    } else {
        int j = i - 4194304;
        int wsel = j >> 20;
        const float* wp = wsel == 0 ? Wq : (wsel == 1 ? Wk : (wsel == 2 ? Wv : Wo));
        s = wp + (j & 1048575);
    }
    float4_a a = *(const float4_a*)s;
    float4_a b = *(const float4_a*)(s + 4);
    short8_a r;
    r[0] = f2bf(a[0]); r[1] = f2bf(a[1]); r[2] = f2bf(a[2]); r[3] = f2bf(a[3]);
    r[4] = f2bf(b[0]); r[5] = f2bf(b[1]); r[6] = f2bf(b[2]); r[7] = f2bf(b[3]);
    *(short8_a*)(out + i) = r;
}

// ---------------- m97-structure GEMM: global_load_lds + linear LDS, BK=32 ----------------
// C[m,n] = sum_k A[m,k] * W[n,k]  (NT form). 4 waves (2x2), wave tile (BM/2)x(BN/2).
// MODE 4: fused QKV (W = [3072][1024] rows = Wq|Wk|Wv). proj = n0>>10:
//   proj 0: Q -> [B,H,T,D] bf16, (acc+bias)*0.125*log2(e)
//   proj 1: K -> [B,H,T,D] bf16
//   proj 2: V -> [B,H,D,T] bf16 (transposed store)
// MODE 3: O -> [T,B,E] fp32
template <int BM, int BN, int MODE>
__global__ __launch_bounds__(256) void gemm_lds(const short* __restrict__ A,
                                                const short* __restrict__ W,
                                                const float* __restrict__ b0,
                                                const float* __restrict__ b1,
                                                const float* __restrict__ b2,
                                                short* __restrict__ o0,
                                                short* __restrict__ o1,
                                                short* __restrict__ o2,
                                                float* __restrict__ of) {
    constexpr int FM = BM / 32;  // 16x16 frags per wave (M)
    constexpr int FN = BN / 32;
    __shared__ short As[BM * 32];  // linear [row][32] shorts (64B rows)
    __shared__ short Bs[BN * 32];

    const int tid = threadIdx.x;
    const int l = tid & 63, w = tid >> 6;
    const int wm = w >> 1, wn = w & 1;
    const int m0 = blockIdx.y * BM, n0 = blockIdx.x * BN;
    const int l15 = l & 15, l4 = l >> 4;
    const int lr = l >> 2, lc = (l & 3) * 8;  // staging lane: 16 rows x 4 chunks per inst

    f32x4 acc[FM][FN];
#pragma unroll
    for (int i = 0; i < FM; i++)
#pragma unroll
        for (int j = 0; j < FN; j++) {
            f32x4 z = {0.f, 0.f, 0.f, 0.f};
            acc[i][j] = z;
        }

    const short* Ab = A + (m0 + lr) * 1024 + lc;
    const short* Wb = W + (n0 + lr) * 1024 + lc;

    for (int k0 = 0; k0 < 1024; k0 += 32) {
        // stage: issue async loads (dest = wave-uniform LDS base)
#pragma unroll
        for (int j = 0; j < BM / 64; j++) {
            int base = (j * 4 + w) * 16;  // 16 rows per inst
            gl_lds16(Ab + base * 1024 + k0, &As[base * 32]);
        }
#pragma unroll
        for (int j = 0; j < BN / 64; j++) {
            int base = (j * 4 + w) * 16;
            gl_lds16(Wb + base * 1024 + k0, &Bs[base * 32]);
        }
        __syncthreads();  // compiler drains vmcnt(0) before s_barrier

        short8_t af[FM], bf[FN];
#pragma unroll
        for (int m = 0; m < FM; m++)
            af[m] = *(const short8_a*)&As[(wm * (BM / 2) + m * 16 + l15) * 32 + l4 * 8];
#pragma unroll
        for (int n = 0; n < FN; n++)
            bf[n] = *(const short8_a*)&Bs[(wn * (BN / 2) + n * 16 + l15) * 32 + l4 * 8];
#pragma unroll
        for (int m = 0; m < FM; m++)
#pragma unroll
            for (int n = 0; n < FN; n++)
                acc[m][n] = __builtin_amdgcn_mfma_f32_16x16x32_bf16(af[m], bf[n], acc[m][n], 0, 0, 0);
        __syncthreads();  // readers done before next stage overwrites
    }

    // epilogue: C/D layout col = lane&15, row = (lane>>4)*4 + i
    if (MODE == 3) {
#pragma unroll
        for (int n = 0; n < FN; n++) {
            int col = n0 + wn * (BN / 2) + n * 16 + l15;
            float bv = b0[col];
#pragma unroll
            for (int m = 0; m < FM; m++)
#pragma unroll
                for (int i = 0; i < 4; i++) {
                    int row = m0 + wm * (BM / 2) + m * 16 + l4 * 4 + i;
                    of[row * 1024 + col] = acc[m][n][i] + bv;
                }
        }
    } else {
        const int proj = n0 >> 10;  // uniform per block
        const float* bias = proj == 0 ? b0 : (proj == 1 ? b1 : b2);
        short* outp = proj == 0 ? o0 : (proj == 1 ? o1 : o2);
#pragma unroll
        for (int n = 0; n < FN; n++) {
            int cw = (n0 + wn * (BN / 2) + n * 16 + l15) & 1023;
            float bv = bias[cw];
            int h = cw >> 6, d = cw & 63;
#pragma unroll
            for (int m = 0; m < FM; m++)
#pragma unroll
                for (int i = 0; i < 4; i++) {
                    int row = m0 + wm * (BM / 2) + m * 16 + l4 * 4 + i;
                    float v = acc[m][n][i] + bv;
                    if (proj == 0) v *= 0.18033688011112042f;  // 0.125 * log2(e)
                    int bb = row & 1, t = row >> 1;
                    if (proj == 2)
                        outp[((bb * 16 + h) * 64 + d) * 2048 + t] = f2bf(v);
                    else
                        outp[((bb * 16 + h) * 2048 + t) * 64 + d] = f2bf(v);
                }
        }
    }
}

__device__ __forceinline__ float max16(const f32x16 v) {
    // balanced tree of triples -> v_max3 fusion, short dep chain
    float a0 = fmaxf(fmaxf(v[0], v[1]), v[2]);
    float a1 = fmaxf(fmaxf(v[3], v[4]), v[5]);
    float a2 = fmaxf(fmaxf(v[6], v[7]), v[8]);
    float a3 = fmaxf(fmaxf(v[9], v[10]), v[11]);
    float a4 = fmaxf(fmaxf(v[12], v[13]), v[14]);
    float b0 = fmaxf(fmaxf(a0, a1), v[15]);
    float b1 = fmaxf(fmaxf(a2, a3), a4);
    return fmaxf(b0, b1);
}

// ---------------- flash attention: 8 waves, in-block KV split ----------------
// Q,K: [B*H][T][64] bf16 (Q pre-scaled by 0.125*log2e). Vt: [B*H][64][T] bf16.
// out: [T*B][1024] bf16. Waves 0-3: KV[0:1024). Waves 4-7: KV[1024:2048).
// Each wave: 32 q-rows. Final combine via LDS (m,l,O rescale-merge).
__global__ __launch_bounds__(512, 4) void flash_attn(const short* __restrict__ Q,
                                                     const short* __restrict__ K,
                                                     const short* __restrict__ Vt,
                                                     short* __restrict__ O) {
    __shared__ short Ks[2][2][64 * 64];  // [group][buf][row][slot], slot = ch ^ (row&7)
    __shared__ short Vs[2][2][64 * 64];

    const int tid = threadIdx.x, l = tid & 63, w = tid >> 6;
    const int g = w >> 2, w4 = w & 3;
    const int l31 = l & 31, hi = l >> 5;
    const int e = l31 & 7;
    const int bh = blockIdx.y;
    const int b = bh >> 4, hh = bh & 15;
    const int qrow = blockIdx.x * 128 + w4 * 32 + l31;

    const short* Qp = Q + bh * (T_DIM * 64);
    const short* Kp = K + bh * (T_DIM * 64) + g * 1024 * 64;  // group's KV row range
    const short* Vp = Vt + bh * (64 * T_DIM) + g * 1024;      // group's V^T col range

    // Q B-frags: B[d = c*16 + hi*8 + j][q = l31]
    short8_t qf[4];
#pragma unroll
    for (int c = 0; c < 4; c++)
        qf[c] = *(const short8_a*)&Qp[qrow * 64 + c * 16 + hi * 8];

    f32x16 oacc[2];
    f32x16 lacc;  // row-sum accumulator via ones-MFMA; only [0] consumed
#pragma unroll
    for (int i = 0; i < 16; i++) { oacc[0][i] = 0.f; oacc[1][i] = 0.f; lacc[i] = 0.f; }
    float mrow = -1e30f;

    short8_t ones;
#pragma unroll
    for (int j = 0; j < 8; j++) ones[j] = (short)0x3F80;  // bf16 1.0

    // staging (per group, 256 threads): 512 chunks (64 rows x 8), 2 per thread
    const int tidg = tid & 255;
    const int srow0 = tidg >> 3, sch = tidg & 7;
    const int srow1 = srow0 + 32;
    const int kslot0 = (sch ^ (srow0 & 7)) * 8;
    const int kslot1 = (sch ^ (srow1 & 7)) * 8;

    short8_t kpre[2], vpre[2];
    kpre[0] = *(const short8_a*)&Kp[srow0 * 64 + sch * 8];
    kpre[1] = *(const short8_a*)&Kp[srow1 * 64 + sch * 8];
    vpre[0] = *(const short8_a*)&Vp[srow0 * 2048 + sch * 8];
    vpre[1] = *(const short8_a*)&Vp[srow1 * 2048 + sch * 8];
    *(short8_a*)&Ks[g][0][srow0 * 64 + kslot0] = kpre[0];
    *(short8_a*)&Ks[g][0][srow1 * 64 + kslot1] = kpre[1];
    *(short8_a*)&Vs[g][0][srow0 * 64 + kslot0] = vpre[0];
    *(short8_a*)&Vs[g][0][srow1 * 64 + kslot1] = vpre[1];

    auto body = [&](const short* kc, const short* vc, short* kn, short* vn, int it) {
        __syncthreads();  // prev iter's reads of (kn,vn) and writes of (kc,vc) done
        if (it + 1 < 16) {  // T14: issue next tile's loads; land during compute
            int s0 = (it + 1) * 64;
            kpre[0] = *(const short8_a*)&Kp[(s0 + srow0) * 64 + sch * 8];
            kpre[1] = *(const short8_a*)&Kp[(s0 + srow1) * 64 + sch * 8];
            vpre[0] = *(const short8_a*)&Vp[srow0 * 2048 + s0 + sch * 8];
            vpre[1] = *(const short8_a*)&Vp[srow1 * 2048 + s0 + sch * 8];
        }

        // ---- QK^T (swapped): St[k][q], lane holds q=l31 col, k in-register ----
        f32x16 st[2];
#pragma unroll
        for (int r = 0; r < 2; r++) {
#pragma unroll
            for (int i = 0; i < 16; i++) st[r][i] = 0.f;
#pragma unroll
            for (int c = 0; c < 4; c++) {
                short8_t kf = *(const short8_a*)&kc[(r * 32 + l31) * 64 + ((2 * c + hi) ^ e) * 8];
                st[r] = __builtin_amdgcn_mfma_f32_32x32x16_bf16(kf, qf[c], st[r], 0, 0, 0);
            }
        }

        // ---- online softmax, defer-max (T13, exp2 domain, THR=8 -> p <= 256) ----
        float pmax = fmaxf(max16(st[0]), max16(st[1]));
        pmax = fmaxf(pmax, __shfl_xor(pmax, 32));
        if (__any(pmax > mrow + 8.f)) {
            float mn = fmaxf(mrow, pmax);
            float sc = exp2f(mrow - mn);
            mrow = mn;
            lacc[0] *= sc;
#pragma unroll
            for (int dd = 0; dd < 2; dd++)
#pragma unroll
                for (int i = 0; i < 16; i++) oacc[dd][i] *= sc;
        }
#pragma unroll
        for (int r = 0; r < 2; r++)
#pragma unroll
            for (int i = 0; i < 16; i++) st[r][i] = exp2f(st[r][i] - mrow);

        // ---- P pack (cvt_pk) + permlane32_swap -> PV B-frags, all in-register ----
#pragma unroll
        for (int r = 0; r < 2; r++) {
            unsigned pk8[8];
#pragma unroll
            for (int u = 0; u < 8; u++) {
                unsigned t;
                asm("v_cvt_pk_bf16_f32 %0, %1, %2" : "=v"(t) : "v"(st[r][2 * u]), "v"(st[r][2 * u + 1]));
                pk8[u] = t;
            }
#pragma unroll
            for (int cc = 0; cc < 2; cc++) {
                unsigned A0 = pk8[4 * cc + 0], B0 = pk8[4 * cc + 2];
                unsigned A1 = pk8[4 * cc + 1], B1 = pk8[4 * cc + 3];
                asm("v_permlane32_swap_b32 %0, %1" : "+v"(A0), "+v"(B0));
                asm("v_permlane32_swap_b32 %0, %1" : "+v"(A1), "+v"(B1));
                u32x4 pu = {A0, A1, B0, B1};
                short8_t pf = __builtin_bit_cast(short8_t, pu);
                // row-sum on the MFMA pipe: all-ones A => every row = sum_k P[k][q]
                lacc = __builtin_amdgcn_mfma_f32_32x32x16_bf16(ones, pf, lacc, 0, 0, 0);
#pragma unroll
                for (int dd = 0; dd < 2; dd++) {
                    short8_t vf = *(const short8_a*)&vc[(dd * 32 + l31) * 64 +
                                                        ((4 * r + 2 * cc + hi) ^ e) * 8];
                    oacc[dd] = __builtin_amdgcn_mfma_f32_32x32x16_bf16(vf, pf, oacc[dd], 0, 0, 0);
                }
            }
        }

        if (it + 1 < 16) {  // write next tile into the other buffer
            *(short8_a*)&kn[srow0 * 64 + kslot0] = kpre[0];
            *(short8_a*)&kn[srow1 * 64 + kslot1] = kpre[1];
            *(short8_a*)&vn[srow0 * 64 + kslot0] = vpre[0];
            *(short8_a*)&vn[srow1 * 64 + kslot1] = vpre[1];
        }
    };

    for (int it = 0; it < 16; it += 2) {
        body(Ks[g][0], Vs[g][0], Ks[g][1], Vs[g][1], it);
        body(Ks[g][1], Vs[g][1], Ks[g][0], Vs[g][0], it + 1);
    }

    // ---- combine the two KV-halves via LDS, then write ----
    __syncthreads();  // all K/V reads done; LDS reusable as exchange buffer
    float* xo = (float*)&Ks[0][0][0];   // 8192 f32: 4 waves x 2048 (O^T partials)
    float* xml = (float*)&Vs[0][0][0];  // 4 waves x 128 (m, l)
    if (g == 1) {
#pragma unroll
        for (int dd = 0; dd < 2; dd++)
#pragma unroll
            for (int g4 = 0; g4 < 4; g4++) {
                f32x4 v = {oacc[dd][4 * g4], oacc[dd][4 * g4 + 1],
                           oacc[dd][4 * g4 + 2], oacc[dd][4 * g4 + 3]};
                *(float4_a*)&xo[w4 * 2048 + (dd * 4 + g4) * 256 + l * 4] = v;
            }
        xml[w4 * 128 + l] = mrow;
        xml[w4 * 128 + 64 + l] = lacc[0];
    }
    __syncthreads();
    if (g == 0) {
        float m1 = xml[w4 * 128 + l];
        float l1 = xml[w4 * 128 + 64 + l];
        float mm = fmaxf(mrow, m1);
        float s0 = exp2f(mrow - mm), s1 = exp2f(m1 - mm);
        float rl = 1.0f / (lacc[0] * s0 + l1 * s1);
        // lane holds O^T[d][q=l31], d = (reg&3)+8*(reg>>2)+4*hi+32*dd
#pragma unroll
        for (int dd = 0; dd < 2; dd++)
#pragma unroll
            for (int g4 = 0; g4 < 4; g4++) {
                f32x4 o1 = *(const float4_a*)&xo[w4 * 2048 + (dd * 4 + g4) * 256 + l * 4];
                short4_t o4;
#pragma unroll
                for (int i = 0; i < 4; i++)
                    o4[i] = f2bf((oacc[dd][4 * g4 + i] * s0 + o1[i] * s1) * rl);
                *(short4_a*)&O[(qrow * 2 + b) * 1024 + hh * 64 + dd * 32 + g4 * 8 + hi * 4] = o4;
            }
    }
}

extern "C" void kernel_launch(void* const* d_in, const int* in_sizes, int n_in,
                              void* d_out, int out_size, void* d_ws, size_t ws_size,
                              hipStream_t stream) {
    const float* query = (const float*)d_in[0];
    const float* Wq = (const float*)d_in[1];
    const float* bq = (const float*)d_in[2];
    const float* Wk = (const float*)d_in[3];
    const float* bk = (const float*)d_in[4];
    const float* Wv = (const float*)d_in[5];
    const float* bv = (const float*)d_in[6];
    const float* Wo = (const float*)d_in[7];
    const float* bo = (const float*)d_in[8];

    // ws layout (shorts). Total = 20,971,520 shorts = 40 MB
    short* Xbf = (short*)d_ws;        // 4096x1024 bf16 query (8 MB) -- reused as attn out
    short* Wqb = Xbf + 4194304;       // Wq|Wk|Wv contiguous = fused [3072][1024]
    short* Wkb = Wqb + 1048576;
    short* Wvb = Wkb + 1048576;
    short* Wob = Wvb + 1048576;
    short* Qb = Wob + 1048576;        // [B,H,T,D] 8 MB
    short* Kb = Qb + 4194304;         // [B,H,T,D] 8 MB
    short* Vtb = Kb + 4194304;        // [B,H,D,T] 8 MB
    short* attnb = Xbf;               // alias: Xbf dead after QKV projection

    // one cvt launch: query + all 4 weights (dst contiguous from Xbf)
    cvt_all<<<4096, 256, 0, stream>>>(query, Wq, Wk, Wv, Wo, Xbf);

    // fused QKV: M=4096, N=3072, 128x128 tiles -> 768 blocks (3/CU)
    gemm_lds<128, 128, 4><<<dim3(24, 32), 256, 0, stream>>>(Xbf, Wqb, bq, bk, bv,
                                                            Qb, Kb, Vtb, nullptr);

    // flash: 512 threads (8 waves, in-block KV split), 512 blocks, 64 KB LDS -> 2 blocks/CU
    flash_attn<<<dim3(16, 32), 512, 0, stream>>>(Qb, Kb, Vtb, attnb);

    // O-proj: M=4096, N=1024, 64x128 tiles -> 512 blocks (2/CU)
    gemm_lds<64, 128, 3><<<dim3(8, 64), 256, 0, stream>>>(attnb, Wob, bo, nullptr, nullptr,
                                                          nullptr, nullptr, nullptr, (float*)d_out);
}

// Round 6
// 142.135 us; speedup vs baseline: 1.2902x; 1.2902x over previous
//
#include <hip/hip_runtime.h>
#include <hip/hip_bf16.h>

#define T_DIM 2048

typedef __attribute__((ext_vector_type(8))) short short8_t;
typedef short8_t __attribute__((may_alias)) short8_a;
typedef __attribute__((ext_vector_type(4))) short short4_t;
typedef short4_t __attribute__((may_alias)) short4_a;
typedef __attribute__((ext_vector_type(4))) float f32x4;
typedef __attribute__((ext_vector_type(16))) float f32x16;
typedef __attribute__((ext_vector_type(4))) float float4_t;
typedef float4_t __attribute__((may_alias)) float4_a;
typedef __attribute__((ext_vector_type(4))) unsigned int u32x4;

__device__ __forceinline__ short f2bf(float f) {
    unsigned int u = __builtin_bit_cast(unsigned int, f);
    unsigned int r = (u + 0x7fffu + ((u >> 16) & 1u)) >> 16;
    return (short)r;
}

// async global->LDS, 16B per lane. lds dst must be wave-uniform base (+ lane*16 implicit).
__device__ __forceinline__ void gl_lds16(const short* g, short* l) {
    __builtin_amdgcn_global_load_lds(
        (const __attribute__((address_space(1))) void*)g,
        (__attribute__((address_space(3))) void*)l, 16, 0, 0);
}

// ---------------- fp32 -> bf16 cast: query + 4 weights in ONE launch ----------------
// dst regions are contiguous in ws: [query 4M][Wq 1M][Wk 1M][Wv 1M][Wo 1M]
__global__ __launch_bounds__(256) void cvt_all(const float* __restrict__ query,
                                               const float* __restrict__ Wq,
                                               const float* __restrict__ Wk,
                                               const float* __restrict__ Wv,
                                               const float* __restrict__ Wo,
                                               short* __restrict__ out) {
    const int bx = blockIdx.x;
    const int i = bx * 2048 + threadIdx.x * 8;
    const float* s;
    if (bx < 2048) {
        s = query + i;
    } else {
        int j = i - 4194304;
        int wsel = j >> 20;
        const float* wp = wsel == 0 ? Wq : (wsel == 1 ? Wk : (wsel == 2 ? Wv : Wo));
        s = wp + (j & 1048575);
    }
    float4_a a = *(const float4_a*)s;
    float4_a b = *(const float4_a*)(s + 4);
    short8_a r;
    r[0] = f2bf(a[0]); r[1] = f2bf(a[1]); r[2] = f2bf(a[2]); r[3] = f2bf(a[3]);
    r[4] = f2bf(b[0]); r[5] = f2bf(b[1]); r[6] = f2bf(b[2]); r[7] = f2bf(b[3]);
    *(short8_a*)(out + i) = r;
}

// ---------------- m97-structure GEMM: global_load_lds + linear LDS, BK=32 ----------------
// C[m,n] = sum_k A[m,k] * W[n,k]  (NT form). 4 waves (2x2), wave tile (BM/2)x(BN/2).
// MODE 4: fused QKV (W = [3072][1024] rows = Wq|Wk|Wv). proj = n0>>10:
//   proj 0: Q -> [B,H,T,D] bf16, (acc+bias)*0.125*log2(e)
//   proj 1: K -> [B,H,T,D] bf16
//   proj 2: V -> [B,H,D,T] bf16 (transposed store)
// MODE 3: O -> [T,B,E] fp32
template <int BM, int BN, int MODE>
__global__ __launch_bounds__(256) void gemm_lds(const short* __restrict__ A,
                                                const short* __restrict__ W,
                                                const float* __restrict__ b0,
                                                const float* __restrict__ b1,
                                                const float* __restrict__ b2,
                                                short* __restrict__ o0,
                                                short* __restrict__ o1,
                                                short* __restrict__ o2,
                                                float* __restrict__ of) {
    constexpr int FM = BM / 32;  // 16x16 frags per wave (M)
    constexpr int FN = BN / 32;
    __shared__ short As[BM * 32];  // linear [row][32] shorts (64B rows)
    __shared__ short Bs[BN * 32];

    const int tid = threadIdx.x;
    const int l = tid & 63, w = tid >> 6;
    const int wm = w >> 1, wn = w & 1;
    const int m0 = blockIdx.y * BM, n0 = blockIdx.x * BN;
    const int l15 = l & 15, l4 = l >> 4;
    const int lr = l >> 2, lc = (l & 3) * 8;  // staging lane: 16 rows x 4 chunks per inst

    f32x4 acc[FM][FN];
#pragma unroll
    for (int i = 0; i < FM; i++)
#pragma unroll
        for (int j = 0; j < FN; j++) {
            f32x4 z = {0.f, 0.f, 0.f, 0.f};
            acc[i][j] = z;
        }

    const short* Ab = A + (m0 + lr) * 1024 + lc;
    const short* Wb = W + (n0 + lr) * 1024 + lc;

    for (int k0 = 0; k0 < 1024; k0 += 32) {
        // stage: issue async loads (dest = wave-uniform LDS base)
#pragma unroll
        for (int j = 0; j < BM / 64; j++) {
            int base = (j * 4 + w) * 16;  // 16 rows per inst
            gl_lds16(Ab + base * 1024 + k0, &As[base * 32]);
        }
#pragma unroll
        for (int j = 0; j < BN / 64; j++) {
            int base = (j * 4 + w) * 16;
            gl_lds16(Wb + base * 1024 + k0, &Bs[base * 32]);
        }
        __syncthreads();  // compiler drains vmcnt(0) before s_barrier

        short8_t af[FM], bf[FN];
#pragma unroll
        for (int m = 0; m < FM; m++)
            af[m] = *(const short8_a*)&As[(wm * (BM / 2) + m * 16 + l15) * 32 + l4 * 8];
#pragma unroll
        for (int n = 0; n < FN; n++)
            bf[n] = *(const short8_a*)&Bs[(wn * (BN / 2) + n * 16 + l15) * 32 + l4 * 8];
#pragma unroll
        for (int m = 0; m < FM; m++)
#pragma unroll
            for (int n = 0; n < FN; n++)
                acc[m][n] = __builtin_amdgcn_mfma_f32_16x16x32_bf16(af[m], bf[n], acc[m][n], 0, 0, 0);
        __syncthreads();  // readers done before next stage overwrites
    }

    // epilogue: C/D layout col = lane&15, row = (lane>>4)*4 + i
    if (MODE == 3) {
#pragma unroll
        for (int n = 0; n < FN; n++) {
            int col = n0 + wn * (BN / 2) + n * 16 + l15;
            float bv = b0[col];
#pragma unroll
            for (int m = 0; m < FM; m++)
#pragma unroll
                for (int i = 0; i < 4; i++) {
                    int row = m0 + wm * (BM / 2) + m * 16 + l4 * 4 + i;
                    of[row * 1024 + col] = acc[m][n][i] + bv;
                }
        }
    } else {
        const int proj = n0 >> 10;  // uniform per block
        const float* bias = proj == 0 ? b0 : (proj == 1 ? b1 : b2);
        short* outp = proj == 0 ? o0 : (proj == 1 ? o1 : o2);
#pragma unroll
        for (int n = 0; n < FN; n++) {
            int cw = (n0 + wn * (BN / 2) + n * 16 + l15) & 1023;
            float bv = bias[cw];
            int h = cw >> 6, d = cw & 63;
#pragma unroll
            for (int m = 0; m < FM; m++)
#pragma unroll
                for (int i = 0; i < 4; i++) {
                    int row = m0 + wm * (BM / 2) + m * 16 + l4 * 4 + i;
                    float v = acc[m][n][i] + bv;
                    if (proj == 0) v *= 0.18033688011112042f;  // 0.125 * log2(e)
                    int bb = row & 1, t = row >> 1;
                    if (proj == 2)
                        outp[((bb * 16 + h) * 64 + d) * 2048 + t] = f2bf(v);
                    else
                        outp[((bb * 16 + h) * 2048 + t) * 64 + d] = f2bf(v);
                }
        }
    }
}

__device__ __forceinline__ float max16(const f32x16 v) {
    // balanced tree of triples -> v_max3 fusion, short dep chain
    float a0 = fmaxf(fmaxf(v[0], v[1]), v[2]);
    float a1 = fmaxf(fmaxf(v[3], v[4]), v[5]);
    float a2 = fmaxf(fmaxf(v[6], v[7]), v[8]);
    float a3 = fmaxf(fmaxf(v[9], v[10]), v[11]);
    float a4 = fmaxf(fmaxf(v[12], v[13]), v[14]);
    float b0 = fmaxf(fmaxf(a0, a1), v[15]);
    float b1 = fmaxf(fmaxf(a2, a3), a4);
    return fmaxf(b0, b1);
}

// ---------------- flash attention (swapped-QKT, 32x32x16, KVBLK=64) ----------------
// R4 structure (4 waves, 256 thr) + XCD swizzle (T1) + global_load_lds staging with
// pre-swizzled per-lane source (m173): LDS linear dest, XOR-swizzle on source & read.
// Q,K: [B*H][T][64] bf16 (Q pre-scaled by 0.125*log2e). Vt: [B*H][64][T] bf16.
__global__ __launch_bounds__(256) void flash_attn(const short* __restrict__ Q,
                                                  const short* __restrict__ K,
                                                  const short* __restrict__ Vt,
                                                  short* __restrict__ O) {
    __shared__ short Ks[2][64 * 64];  // [row][slot], slot = ch ^ (row&7), chunk = 8 shorts
    __shared__ short Vs[2][64 * 64];

    const int tid = threadIdx.x, l = tid & 63, w = tid >> 6;
    const int l31 = l & 31, hi = l >> 5;
    const int e = l31 & 7;

    // T1: group all 16 q-tiles of one bh on one XCD (hw bid % 8 = XCD)
    const int bid = blockIdx.x + (blockIdx.y << 4);      // 0..511, x-major
    const int swz = (bid & 7) * 64 + (bid >> 3);         // bijective (512 % 8 == 0)
    const int qt = swz & 15, bh = swz >> 4;

    const int b = bh >> 4, hh = bh & 15;
    const int qrow = qt * 128 + w * 32 + l31;

    const short* Qp = Q + bh * (T_DIM * 64);
    const short* Kp = K + bh * (T_DIM * 64);
    const short* Vp = Vt + bh * (64 * T_DIM);

    // Q B-frags: B[d = c*16 + hi*8 + j][q = l31]
    short8_t qf[4];
#pragma unroll
    for (int c = 0; c < 4; c++)
        qf[c] = *(const short8_a*)&Qp[qrow * 64 + c * 16 + hi * 8];

    f32x16 oacc[2];
    f32x16 lacc;  // row-sum accumulator via ones-MFMA; only [0] consumed
#pragma unroll
    for (int i = 0; i < 16; i++) { oacc[0][i] = 0.f; oacc[1][i] = 0.f; lacc[i] = 0.f; }
    float mrow = -1e30f;

    short8_t ones;
#pragma unroll
    for (int j = 0; j < 8; j++) ones[j] = (short)0x3F80;  // bf16 1.0

    // staging via gl_lds: inst j covers LDS rows j*8..j*8+7 (1 KB); wave w takes j=2w,2w+1
    // lane: lrow = l>>3 (row within inst), slot = l&7; source chunk = slot ^ (row&7)
    const int lrow = l >> 3;
    const int lch = (l & 7) ^ (lrow & 7);  // pre-swizzled global chunk
    const int j0 = 2 * w, j1 = 2 * w + 1;
    const short* kg0 = Kp + (j0 * 8 + lrow) * 64 + lch * 8;
    const short* kg1 = Kp + (j1 * 8 + lrow) * 64 + lch * 8;
    const short* vg0 = Vp + (j0 * 8 + lrow) * 2048 + lch * 8;
    const short* vg1 = Vp + (j1 * 8 + lrow) * 2048 + lch * 8;

    auto stage = [&](int it, int buf) {
        const int koff = it * 4096;  // 64 rows * 64
        const int voff = it * 64;    // 64 cols in V^T
        gl_lds16(kg0 + koff, &Ks[buf][j0 * 512]);
        gl_lds16(kg1 + koff, &Ks[buf][j1 * 512]);
        gl_lds16(vg0 + voff, &Vs[buf][j0 * 512]);
        gl_lds16(vg1 + voff, &Vs[buf][j1 * 512]);
    };

    stage(0, 0);

    for (int it = 0; it < 32; ++it) {
        const int cur = it & 1;
        __syncthreads();  // drains vmcnt -> buf[cur] staged; prev readers of buf[cur^1] done
        if (it + 1 < 32) stage(it + 1, cur ^ 1);  // fire-and-forget into the free buffer

        const short* kc = Ks[cur];
        const short* vc = Vs[cur];

        // ---- QK^T (swapped): St[k][q], lane holds q=l31 col, k in-register ----
        f32x16 st[2];
#pragma unroll
        for (int r = 0; r < 2; r++) {
#pragma unroll
            for (int i = 0; i < 16; i++) st[r][i] = 0.f;
#pragma unroll
            for (int c = 0; c < 4; c++) {
                short8_t kf = *(const short8_a*)&kc[(r * 32 + l31) * 64 + ((2 * c + hi) ^ e) * 8];
                st[r] = __builtin_amdgcn_mfma_f32_32x32x16_bf16(kf, qf[c], st[r], 0, 0, 0);
            }
        }

        // ---- online softmax, defer-max (T13, exp2 domain, THR=8 -> p <= 256) ----
        float pmax = fmaxf(max16(st[0]), max16(st[1]));
        pmax = fmaxf(pmax, __shfl_xor(pmax, 32));
        if (__any(pmax > mrow + 8.f)) {
            float mn = fmaxf(mrow, pmax);
            float sc = exp2f(mrow - mn);
            mrow = mn;
            lacc[0] *= sc;
#pragma unroll
            for (int dd = 0; dd < 2; dd++)
#pragma unroll
                for (int i = 0; i < 16; i++) oacc[dd][i] *= sc;
        }
#pragma unroll
        for (int r = 0; r < 2; r++)
#pragma unroll
            for (int i = 0; i < 16; i++) st[r][i] = exp2f(st[r][i] - mrow);

        // ---- P pack (cvt_pk) + permlane32_swap -> PV B-frags, all in-register ----
#pragma unroll
        for (int r = 0; r < 2; r++) {
            unsigned pk8[8];
#pragma unroll
            for (int u = 0; u < 8; u++) {
                unsigned t;
                asm("v_cvt_pk_bf16_f32 %0, %1, %2" : "=v"(t) : "v"(st[r][2 * u]), "v"(st[r][2 * u + 1]));
                pk8[u] = t;
            }
#pragma unroll
            for (int cc = 0; cc < 2; cc++) {
                unsigned A0 = pk8[4 * cc + 0], B0 = pk8[4 * cc + 2];
                unsigned A1 = pk8[4 * cc + 1], B1 = pk8[4 * cc + 3];
                asm("v_permlane32_swap_b32 %0, %1" : "+v"(A0), "+v"(B0));
                asm("v_permlane32_swap_b32 %0, %1" : "+v"(A1), "+v"(B1));
                u32x4 pu = {A0, A1, B0, B1};
                short8_t pf = __builtin_bit_cast(short8_t, pu);
                // row-sum on the MFMA pipe: all-ones A => every row = sum_k P[k][q]
                lacc = __builtin_amdgcn_mfma_f32_32x32x16_bf16(ones, pf, lacc, 0, 0, 0);
#pragma unroll
                for (int dd = 0; dd < 2; dd++) {
                    short8_t vf = *(const short8_a*)&vc[(dd * 32 + l31) * 64 +
                                                        ((4 * r + 2 * cc + hi) ^ e) * 8];
                    oacc[dd] = __builtin_amdgcn_mfma_f32_32x32x16_bf16(vf, pf, oacc[dd], 0, 0, 0);
                }
            }
        }
    }

    // ---- epilogue: lane holds O^T[d][q=l31], d = (reg&3)+8*(reg>>2)+4*hi+32*dd ----
    float rl = 1.0f / lacc[0];
#pragma unroll
    for (int dd = 0; dd < 2; dd++)
#pragma unroll
        for (int g = 0; g < 4; g++) {
            short4_t o4;
#pragma unroll
            for (int i = 0; i < 4; i++) o4[i] = f2bf(oacc[dd][4 * g + i] * rl);
            *(short4_a*)&O[(qrow * 2 + b) * 1024 + hh * 64 + dd * 32 + g * 8 + hi * 4] = o4;
        }
}

extern "C" void kernel_launch(void* const* d_in, const int* in_sizes, int n_in,
                              void* d_out, int out_size, void* d_ws, size_t ws_size,
                              hipStream_t stream) {
    const float* query = (const float*)d_in[0];
    const float* Wq = (const float*)d_in[1];
    const float* bq = (const float*)d_in[2];
    const float* Wk = (const float*)d_in[3];
    const float* bk = (const float*)d_in[4];
    const float* Wv = (const float*)d_in[5];
    const float* bv = (const float*)d_in[6];
    const float* Wo = (const float*)d_in[7];
    const float* bo = (const float*)d_in[8];

    // ws layout (shorts). Total = 20,971,520 shorts = 40 MB
    short* Xbf = (short*)d_ws;        // 4096x1024 bf16 query (8 MB) -- reused as attn out
    short* Wqb = Xbf + 4194304;       // Wq|Wk|Wv contiguous = fused [3072][1024]
    short* Wkb = Wqb + 1048576;
    short* Wvb = Wkb + 1048576;
    short* Wob = Wvb + 1048576;
    short* Qb = Wob + 1048576;        // [B,H,T,D] 8 MB
    short* Kb = Qb + 4194304;         // [B,H,T,D] 8 MB
    short* Vtb = Kb + 4194304;        // [B,H,D,T] 8 MB
    short* attnb = Xbf;               // alias: Xbf dead after QKV projection

    // one cvt launch: query + all 4 weights (dst contiguous from Xbf)
    cvt_all<<<4096, 256, 0, stream>>>(query, Wq, Wk, Wv, Wo, Xbf);

    // fused QKV: M=4096, N=3072, 128x128 tiles -> 768 blocks (3/CU)
    gemm_lds<128, 128, 4><<<dim3(24, 32), 256, 0, stream>>>(Xbf, Wqb, bq, bk, bv,
                                                            Qb, Kb, Vtb, nullptr);

    // flash: 256 threads (4 waves), 512 blocks, 32 KB LDS
    flash_attn<<<dim3(16, 32), 256, 0, stream>>>(Qb, Kb, Vtb, attnb);

    // O-proj: M=4096, N=1024, 64x128 tiles -> 512 blocks (2/CU)
    gemm_lds<64, 128, 3><<<dim3(8, 64), 256, 0, stream>>>(attnb, Wob, bo, nullptr, nullptr,
                                                          nullptr, nullptr, nullptr, (float*)d_out);
}

// Round 7
// 136.264 us; speedup vs baseline: 1.3458x; 1.0431x over previous
//
#include <hip/hip_runtime.h>
#include <hip/hip_bf16.h>

#define T_DIM 2048

typedef __attribute__((ext_vector_type(8))) short short8_t;
typedef short8_t __attribute__((may_alias)) short8_a;
typedef __attribute__((ext_vector_type(4))) short short4_t;
typedef short4_t __attribute__((may_alias)) short4_a;
typedef __attribute__((ext_vector_type(4))) float f32x4;
typedef __attribute__((ext_vector_type(16))) float f32x16;
typedef __attribute__((ext_vector_type(4))) float float4_t;
typedef float4_t __attribute__((may_alias)) float4_a;
typedef __attribute__((ext_vector_type(4))) unsigned int u32x4;

__device__ __forceinline__ short f2bf(float f) {
    unsigned int u = __builtin_bit_cast(unsigned int, f);
    unsigned int r = (u + 0x7fffu + ((u >> 16) & 1u)) >> 16;
    return (short)r;
}

// async global->LDS, 16B per lane. lds dst must be wave-uniform base (+ lane*16 implicit).
__device__ __forceinline__ void gl_lds16(const short* g, short* l) {
    __builtin_amdgcn_global_load_lds(
        (const __attribute__((address_space(1))) void*)g,
        (__attribute__((address_space(3))) void*)l, 16, 0, 0);
}

// ---------------- fp32 -> bf16 cast: query + 4 weights in ONE launch ----------------
__global__ __launch_bounds__(256) void cvt_all(const float* __restrict__ query,
                                               const float* __restrict__ Wq,
                                               const float* __restrict__ Wk,
                                               const float* __restrict__ Wv,
                                               const float* __restrict__ Wo,
                                               short* __restrict__ out) {
    const int bx = blockIdx.x;
    const int i = bx * 2048 + threadIdx.x * 8;
    const float* s;
    if (bx < 2048) {
        s = query + i;
    } else {
        int j = i - 4194304;
        int wsel = j >> 20;
        const float* wp = wsel == 0 ? Wq : (wsel == 1 ? Wk : (wsel == 2 ? Wv : Wo));
        s = wp + (j & 1048575);
    }
    float4_a a = *(const float4_a*)s;
    float4_a b = *(const float4_a*)(s + 4);
    short8_a r;
    r[0] = f2bf(a[0]); r[1] = f2bf(a[1]); r[2] = f2bf(a[2]); r[3] = f2bf(a[3]);
    r[4] = f2bf(b[0]); r[5] = f2bf(b[1]); r[6] = f2bf(b[2]); r[7] = f2bf(b[3]);
    *(short8_a*)(out + i) = r;
}

// ---------------- m97-structure GEMM: global_load_lds + linear LDS, BK=32 ----------------
template <int BM, int BN, int MODE>
__global__ __launch_bounds__(256) void gemm_lds(const short* __restrict__ A,
                                                const short* __restrict__ W,
                                                const float* __restrict__ b0,
                                                const float* __restrict__ b1,
                                                const float* __restrict__ b2,
                                                short* __restrict__ o0,
                                                short* __restrict__ o1,
                                                short* __restrict__ o2,
                                                float* __restrict__ of) {
    constexpr int FM = BM / 32;
    constexpr int FN = BN / 32;
    __shared__ short As[BM * 32];
    __shared__ short Bs[BN * 32];

    const int tid = threadIdx.x;
    const int l = tid & 63, w = tid >> 6;
    const int wm = w >> 1, wn = w & 1;
    const int m0 = blockIdx.y * BM, n0 = blockIdx.x * BN;
    const int l15 = l & 15, l4 = l >> 4;
    const int lr = l >> 2, lc = (l & 3) * 8;

    f32x4 acc[FM][FN];
#pragma unroll
    for (int i = 0; i < FM; i++)
#pragma unroll
        for (int j = 0; j < FN; j++) {
            f32x4 z = {0.f, 0.f, 0.f, 0.f};
            acc[i][j] = z;
        }

    const short* Ab = A + (m0 + lr) * 1024 + lc;
    const short* Wb = W + (n0 + lr) * 1024 + lc;

    for (int k0 = 0; k0 < 1024; k0 += 32) {
#pragma unroll
        for (int j = 0; j < BM / 64; j++) {
            int base = (j * 4 + w) * 16;
            gl_lds16(Ab + base * 1024 + k0, &As[base * 32]);
        }
#pragma unroll
        for (int j = 0; j < BN / 64; j++) {
            int base = (j * 4 + w) * 16;
            gl_lds16(Wb + base * 1024 + k0, &Bs[base * 32]);
        }
        __syncthreads();

        short8_t af[FM], bf[FN];
#pragma unroll
        for (int m = 0; m < FM; m++)
            af[m] = *(const short8_a*)&As[(wm * (BM / 2) + m * 16 + l15) * 32 + l4 * 8];
#pragma unroll
        for (int n = 0; n < FN; n++)
            bf[n] = *(const short8_a*)&Bs[(wn * (BN / 2) + n * 16 + l15) * 32 + l4 * 8];
#pragma unroll
        for (int m = 0; m < FM; m++)
#pragma unroll
            for (int n = 0; n < FN; n++)
                acc[m][n] = __builtin_amdgcn_mfma_f32_16x16x32_bf16(af[m], bf[n], acc[m][n], 0, 0, 0);
        __syncthreads();
    }

    if (MODE == 3) {
#pragma unroll
        for (int n = 0; n < FN; n++) {
            int col = n0 + wn * (BN / 2) + n * 16 + l15;
            float bv = b0[col];
#pragma unroll
            for (int m = 0; m < FM; m++)
#pragma unroll
                for (int i = 0; i < 4; i++) {
                    int row = m0 + wm * (BM / 2) + m * 16 + l4 * 4 + i;
                    of[row * 1024 + col] = acc[m][n][i] + bv;
                }
        }
    } else {
        const int proj = n0 >> 10;
        const float* bias = proj == 0 ? b0 : (proj == 1 ? b1 : b2);
        short* outp = proj == 0 ? o0 : (proj == 1 ? o1 : o2);
#pragma unroll
        for (int n = 0; n < FN; n++) {
            int cw = (n0 + wn * (BN / 2) + n * 16 + l15) & 1023;
            float bv = bias[cw];
            int h = cw >> 6, d = cw & 63;
#pragma unroll
            for (int m = 0; m < FM; m++)
#pragma unroll
                for (int i = 0; i < 4; i++) {
                    int row = m0 + wm * (BM / 2) + m * 16 + l4 * 4 + i;
                    float v = acc[m][n][i] + bv;
                    if (proj == 0) v *= 0.18033688011112042f;  // 0.125 * log2(e)
                    int bb = row & 1, t = row >> 1;
                    if (proj == 2)
                        outp[((bb * 16 + h) * 64 + d) * 2048 + t] = f2bf(v);
                    else
                        outp[((bb * 16 + h) * 2048 + t) * 64 + d] = f2bf(v);
                }
        }
    }
}

__device__ __forceinline__ float max16(const f32x16 v) {
    float a0 = fmaxf(fmaxf(v[0], v[1]), v[2]);
    float a1 = fmaxf(fmaxf(v[3], v[4]), v[5]);
    float a2 = fmaxf(fmaxf(v[6], v[7]), v[8]);
    float a3 = fmaxf(fmaxf(v[9], v[10]), v[11]);
    float a4 = fmaxf(fmaxf(v[12], v[13]), v[14]);
    float b0 = fmaxf(fmaxf(a0, a1), v[15]);
    float b1 = fmaxf(fmaxf(a2, a3), a4);
    return fmaxf(b0, b1);
}

// ---------------- flash attention: T15 3-stream pipeline ----------------
// Per iter i: QK(i+1) [MFMA] || softmax(i) [VALU/TRANS] || PV(i-1) [MFMA] -- independent.
// 4-deep LDS ring, single barrier/iter, gl_lds staging prefetch-2, XCD swizzle.
// Q,K: [B*H][T][64] bf16 (Q pre-scaled by 0.125*log2e). Vt: [B*H][64][T] bf16.
__global__ __launch_bounds__(256) void flash_attn(const short* __restrict__ Q,
                                                  const short* __restrict__ K,
                                                  const short* __restrict__ Vt,
                                                  short* __restrict__ O) {
    __shared__ short Ks[4][64 * 64];  // [slot][row][chunk ^ (row&7)]
    __shared__ short Vs[4][64 * 64];

    const int tid = threadIdx.x, l = tid & 63, w = tid >> 6;
    const int l31 = l & 31, hi = l >> 5;
    const int e = l31 & 7;

    // T1: all 16 q-tiles of one bh on one XCD (hw bid % 8 = XCD)
    const int bid = blockIdx.x + (blockIdx.y << 4);
    const int swz = (bid & 7) * 64 + (bid >> 3);
    const int qt = swz & 15, bh = swz >> 4;

    const int b = bh >> 4, hh = bh & 15;
    const int qrow = qt * 128 + w * 32 + l31;

    const short* Qp = Q + bh * (T_DIM * 64);
    const short* Kp = K + bh * (T_DIM * 64);
    const short* Vp = Vt + bh * (64 * T_DIM);

    short8_t qf[4];
#pragma unroll
    for (int c = 0; c < 4; c++)
        qf[c] = *(const short8_a*)&Qp[qrow * 64 + c * 16 + hi * 8];

    f32x16 oacc[2];
    f32x16 lacc;
#pragma unroll
    for (int i = 0; i < 16; i++) { oacc[0][i] = 0.f; oacc[1][i] = 0.f; lacc[i] = 0.f; }
    float mrow = -1e30f;

    short8_t ones;
#pragma unroll
    for (int j = 0; j < 8; j++) ones[j] = (short)0x3F80;  // bf16 1.0

    // gl_lds staging: inst j covers LDS rows j*8..j*8+7; wave w takes j=2w,2w+1
    const int lrow = l >> 3;
    const int lch = (l & 7) ^ (lrow & 7);  // pre-swizzled source chunk
    const int j0 = 2 * w, j1 = 2 * w + 1;
    const short* kg0 = Kp + (j0 * 8 + lrow) * 64 + lch * 8;
    const short* kg1 = Kp + (j1 * 8 + lrow) * 64 + lch * 8;
    const short* vg0 = Vp + (j0 * 8 + lrow) * 2048 + lch * 8;
    const short* vg1 = Vp + (j1 * 8 + lrow) * 2048 + lch * 8;

    auto stage = [&](int it) {
        const int buf = it & 3;
        const int koff = it * 4096, voff = it * 64;
        gl_lds16(kg0 + koff, &Ks[buf][j0 * 512]);
        gl_lds16(kg1 + koff, &Ks[buf][j1 * 512]);
        gl_lds16(vg0 + voff, &Vs[buf][j0 * 512]);
        gl_lds16(vg1 + voff, &Vs[buf][j1 * 512]);
    };

    // QK(t) from slot t&3 into st[2]
    auto qk = [&](f32x16* st, int t) {
        const short* kc = &Ks[t & 3][0];
        f32x16 z;
#pragma unroll
        for (int i = 0; i < 16; i++) z[i] = 0.f;
        st[0] = z; st[1] = z;
#pragma unroll
        for (int c = 0; c < 4; c++) {
            short8_t kf0 = *(const short8_a*)&kc[(l31) * 64 + ((2 * c + hi) ^ e) * 8];
            short8_t kf1 = *(const short8_a*)&kc[(32 + l31) * 64 + ((2 * c + hi) ^ e) * 8];
            st[0] = __builtin_amdgcn_mfma_f32_32x32x16_bf16(kf0, qf[c], st[0], 0, 0, 0);
            st[1] = __builtin_amdgcn_mfma_f32_32x32x16_bf16(kf1, qf[c], st[1], 0, 0, 0);
        }
    };

    // PV(t) with packed frags pf[4] from slot t&3
    auto pv = [&](const short8_t* pf, int t) {
        const short* vc = &Vs[t & 3][0];
#pragma unroll
        for (int r = 0; r < 2; r++)
#pragma unroll
            for (int cc = 0; cc < 2; cc++) {
                short8_t p = pf[r * 2 + cc];
                lacc = __builtin_amdgcn_mfma_f32_32x32x16_bf16(ones, p, lacc, 0, 0, 0);
#pragma unroll
                for (int dd = 0; dd < 2; dd++) {
                    short8_t vf = *(const short8_a*)&vc[(dd * 32 + l31) * 64 +
                                                        ((4 * r + 2 * cc + hi) ^ e) * 8];
                    oacc[dd] = __builtin_amdgcn_mfma_f32_32x32x16_bf16(vf, p, oacc[dd], 0, 0, 0);
                }
            }
    };

    // exp + pack st -> pf[4]
    auto expack = [&](f32x16* st, short8_t* pf) {
#pragma unroll
        for (int r = 0; r < 2; r++) {
#pragma unroll
            for (int i = 0; i < 16; i++) st[r][i] = exp2f(st[r][i] - mrow);
            unsigned pk8[8];
#pragma unroll
            for (int u = 0; u < 8; u++) {
                unsigned t;
                asm("v_cvt_pk_bf16_f32 %0, %1, %2" : "=v"(t) : "v"(st[r][2 * u]), "v"(st[r][2 * u + 1]));
                pk8[u] = t;
            }
#pragma unroll
            for (int cc = 0; cc < 2; cc++) {
                unsigned A0 = pk8[4 * cc + 0], B0 = pk8[4 * cc + 2];
                unsigned A1 = pk8[4 * cc + 1], B1 = pk8[4 * cc + 3];
                asm("v_permlane32_swap_b32 %0, %1" : "+v"(A0), "+v"(B0));
                asm("v_permlane32_swap_b32 %0, %1" : "+v"(A1), "+v"(B1));
                u32x4 pu = {A0, A1, B0, B1};
                pf[r * 2 + cc] = __builtin_bit_cast(short8_t, pu);
            }
        }
    };

    f32x16 stA[2], stB[2];
    short8_t pfA[4], pfB[4];

    // prologue: tile 0 staged+scored
    stage(0);
    __syncthreads();
    stage(1);
    qk(stB, 0);  // stB = S(0)

    // iter i: scores(i) in stCur; produce pfOut = P(i); consume pfIn = P(i-1)
    auto halfiter = [&](f32x16* stCur, f32x16* stNext, short8_t* pfIn, short8_t* pfOut, int i) {
        __syncthreads();                 // tile i+1 visible; skew bound
        if (i + 2 < 32) stage(i + 2);    // into slot (i+2)&3 == (i-2)&3, consumed long ago
        // softmax head (independent, hoistable): pmax of S(i)
        float pmax = fmaxf(max16(stCur[0]), max16(stCur[1]));
        pmax = fmaxf(pmax, __shfl_xor(pmax, 32));
        if (i + 1 < 32) qk(stNext, i + 1);   // MFMA stream 1
        if (i > 0) pv(pfIn, i - 1);          // MFMA stream 2
        // deferred rescale -- AFTER pv(i-1) in program order (oacc RAW keeps it correct)
        if (__any(pmax > mrow + 8.f)) {
            float mn = fmaxf(mrow, pmax);
            float sc = exp2f(mrow - mn);
            mrow = mn;
            lacc[0] *= sc;
#pragma unroll
            for (int dd = 0; dd < 2; dd++)
#pragma unroll
                for (int ii = 0; ii < 16; ii++) oacc[dd][ii] *= sc;
        }
        expack(stCur, pfOut);  // TRANS/VALU stream (interleaves with MFMAs above)
    };

    for (int i = 0; i < 32; i += 2) {
        halfiter(stB, stA, pfA, pfB, i);
        halfiter(stA, stB, pfB, pfA, i + 1);
    }
    // epilogue: PV(31) with pfA (= P(31)), V in slot 3 (staged at i=29, synced at i=30)
    pv(pfA, 31);

    float rl = 1.0f / lacc[0];
#pragma unroll
    for (int dd = 0; dd < 2; dd++)
#pragma unroll
        for (int g = 0; g < 4; g++) {
            short4_t o4;
#pragma unroll
            for (int i = 0; i < 4; i++) o4[i] = f2bf(oacc[dd][4 * g + i] * rl);
            *(short4_a*)&O[(qrow * 2 + b) * 1024 + hh * 64 + dd * 32 + g * 8 + hi * 4] = o4;
        }
}

extern "C" void kernel_launch(void* const* d_in, const int* in_sizes, int n_in,
                              void* d_out, int out_size, void* d_ws, size_t ws_size,
                              hipStream_t stream) {
    const float* query = (const float*)d_in[0];
    const float* Wq = (const float*)d_in[1];
    const float* bq = (const float*)d_in[2];
    const float* Wk = (const float*)d_in[3];
    const float* bk = (const float*)d_in[4];
    const float* Wv = (const float*)d_in[5];
    const float* bv = (const float*)d_in[6];
    const float* Wo = (const float*)d_in[7];
    const float* bo = (const float*)d_in[8];

    short* Xbf = (short*)d_ws;        // 4096x1024 bf16 query (8 MB) -- reused as attn out
    short* Wqb = Xbf + 4194304;       // Wq|Wk|Wv contiguous = fused [3072][1024]
    short* Wkb = Wqb + 1048576;
    short* Wvb = Wkb + 1048576;
    short* Wob = Wvb + 1048576;
    short* Qb = Wob + 1048576;        // [B,H,T,D] 8 MB
    short* Kb = Qb + 4194304;         // [B,H,T,D] 8 MB
    short* Vtb = Kb + 4194304;        // [B,H,D,T] 8 MB
    short* attnb = Xbf;

    cvt_all<<<4096, 256, 0, stream>>>(query, Wq, Wk, Wv, Wo, Xbf);

    gemm_lds<128, 128, 4><<<dim3(24, 32), 256, 0, stream>>>(Xbf, Wqb, bq, bk, bv,
                                                            Qb, Kb, Vtb, nullptr);

    flash_attn<<<dim3(16, 32), 256, 0, stream>>>(Qb, Kb, Vtb, attnb);

    gemm_lds<64, 128, 3><<<dim3(8, 64), 256, 0, stream>>>(attnb, Wob, bo, nullptr, nullptr,
                                                          nullptr, nullptr, nullptr, (float*)d_out);
}